// Round 7
// baseline (172.995 us; speedup 1.0000x reference)
//
#include <hip/hip_runtime.h>

typedef unsigned short u16;
using short8  = __attribute__((ext_vector_type(8))) short;
using float4v = __attribute__((ext_vector_type(4))) float;

__device__ __forceinline__ u16 f2bf(float f) {
    union { float f; unsigned u; } v; v.f = f;
    unsigned r = (v.u + 0x7fff + ((v.u >> 16) & 1)) >> 16;
    return (u16)r;
}
__device__ __forceinline__ float bf2f(u16 h) {
    union { unsigned u; float f; } v; v.u = ((unsigned)h) << 16; return v.f;
}
// HW packed f32x2 -> bf16x2 (lo in low 16 bits). CDNA3+/gfx950.
__device__ __forceinline__ unsigned pkbf(float lo, float hi) {
    unsigned d;
    asm("v_cvt_pk_bf16_f32 %0, %1, %2" : "=v"(d) : "v"(lo), "v"(hi));
    return d;
}
// sin(2*pi*r): v_fract then hardware v_sin (input in revolutions).
__device__ __forceinline__ float sin_rev(float r) {
    float f, s;
    asm("v_fract_f32 %0, %1" : "=v"(f) : "v"(r));
    asm("v_sin_f32 %0, %1" : "=v"(s) : "v"(f));
    return s;
}
__device__ __forceinline__ void dma16(const void* g, void* l) {
    __builtin_amdgcn_global_load_lds((const __attribute__((address_space(1))) void*)g,
                                     (__attribute__((address_space(3))) void*)l, 16, 0, 0);
}

// ---------------------------------------------------------------------------
// merged f32 -> bf16 bulk convert for five tensors + PD precompute
// ---------------------------------------------------------------------------
__device__ __forceinline__ void cvt4(const float* __restrict__ s, u16* __restrict__ o, int i) {
    float4 v = ((const float4*)s)[i];
    uint2 r; r.x = pkbf(v.x, v.y); r.y = pkbf(v.z, v.w);
    ((uint2*)o)[i] = r;
}

__global__ __launch_bounds__(256)
void cvt_all(const float* __restrict__ s0, const float* __restrict__ s1,
             const float* __restrict__ s2, const float* __restrict__ s3,
             const float* __restrict__ s4, const float* __restrict__ prois,
             u16* __restrict__ o0, u16* __restrict__ o1, u16* __restrict__ o2,
             u16* __restrict__ o3, u16* __restrict__ o4, float4* __restrict__ PD,
             int na4, int nb4, int nw4, int PT) {
    int i = blockIdx.x * 256 + threadIdx.x;
    if (i < na4) { cvt4(s0, o0, i); return; }
    i -= na4;
    if (i < nb4) { cvt4(s1, o1, i); return; }
    i -= nb4;
    if (i < nw4) { cvt4(s2, o2, i); return; }
    i -= nw4;
    if (i < nw4) { cvt4(s3, o3, i); return; }
    i -= nw4;
    if (i < nw4) { cvt4(s4, o4, i); return; }
    i -= nw4;
    if (i < PT) {
        const float* pr = prois + (size_t)i * 5;
        float pxmin = pr[1], pymin = pr[2], pxmax = pr[3], pymax = pr[4];
        PD[i] = make_float4(0.5f * (pxmin + pxmax), 0.5f * (pymin + pymax),
                            __logf(pxmax - pxmin + 1.0f), __logf(pymax - pymin + 1.0f));
    }
}

// ---------------------------------------------------------------------------
// proj_posw: fused proj GEMMs (MFMA-bound) + posw embedding (VALU-bound),
// interleaved 3:8 per group of 11 blocks. LDS 24 KB -> 6 blocks/CU.
//   proj:  Tr epilogue buffer aliases As/Ws (dead after k-loop).
//   posw:  r6 sin-chain numerics; stage/flush in two 8-iter halves (r4's
//          proven flush) to halve the posw LDS footprint.
// ---------------------------------------------------------------------------
__global__ __launch_bounds__(256)
void proj_posw(const u16* __restrict__ Ab, const u16* __restrict__ Pb,
               const u16* __restrict__ Wqb, const u16* __restrict__ Wkb,
               const u16* __restrict__ Cwb, const float* __restrict__ bq,
               const float* __restrict__ bk, u16* __restrict__ Qb,
               u16* __restrict__ Kb, u16* __restrict__ PVt,
               const float* __restrict__ rois, const float4* __restrict__ PD,
               const float* __restrict__ Wg_w, const float* __restrict__ Wg_b,
               u16* __restrict__ POSW, const int* __restrict__ n1b_p,
               const int* __restrict__ n1p_p, int PT) {
    __shared__ __align__(16) u16 SH[12288];   // 24 KB

    const int grp = blockIdx.x / 11, rem = blockIdx.x % 11;
    const int t = threadIdx.x;
    const int w = t >> 6, lane = t & 63;
    const int fm = lane & 15, quad = lane >> 4;

    if (rem < 3) {
        // ================= proj path =================
        u16* As = SH;             // [128][64]  16 KB
        u16* Ws = SH + 8192;      // [64][64]    8 KB
        u16* Tr = SH;             // aliases As/Ws after the k-loop (8704 u16)
        const int pb = grp * 3 + rem;
        const int z = pb >> 8;
        const int m0 = ((pb >> 4) & 15) * 128, j0 = (pb & 15) * 64;
        const u16* A = (z == 0) ? Ab : Pb;
        const u16* W = (z == 0) ? Wqb : (z == 1 ? Wkb : Cwb);
        const int wm = w >> 1, wn = w & 1;
        const int lr = lane >> 3, lc = lane & 7, gch = lc ^ lr;

        float4v zero4 = {0.f, 0.f, 0.f, 0.f};
        float4v acc[4][2];
#pragma unroll
        for (int i = 0; i < 4; ++i) { acc[i][0] = zero4; acc[i][1] = zero4; }

        for (int k0 = 0; k0 < 1024; k0 += 64) {
#pragma unroll
            for (int i = 0; i < 4; ++i) {
                int row = w * 32 + i * 8 + lr;
                dma16(A + (size_t)(m0 + row) * 1024 + k0 + gch * 8,
                      As + (w * 32 + i * 8) * 64 + lane * 8);
            }
#pragma unroll
            for (int i = 0; i < 2; ++i) {
                int row = w * 16 + i * 8 + lr;
                dma16(W + (size_t)(j0 + row) * 1024 + k0 + gch * 8,
                      Ws + (w * 16 + i * 8) * 64 + lane * 8);
            }
            __syncthreads();
#pragma unroll
            for (int ks = 0; ks < 2; ++ks) {
                int c = ks * 4 + quad;
                short8 af[4], bf[2];
#pragma unroll
                for (int i = 0; i < 4; ++i) {
                    int ra = wm * 64 + i * 16 + fm;
                    af[i] = *(const short8*)(As + ra * 64 + ((c ^ (ra & 7)) * 8));
                }
#pragma unroll
                for (int j = 0; j < 2; ++j) {
                    int rb = wn * 32 + j * 16 + fm;
                    bf[j] = *(const short8*)(Ws + rb * 64 + ((c ^ (rb & 7)) * 8));
                }
#pragma unroll
                for (int i = 0; i < 4; ++i)
#pragma unroll
                    for (int j = 0; j < 2; ++j)
                        acc[i][j] = __builtin_amdgcn_mfma_f32_16x16x32_bf16(af[i], bf[j], acc[i][j], 0, 0, 0);
            }
            __syncthreads();
        }
        // k-loop ended with a barrier: As/Ws dead, Tr (alias) safe to write.

        if (z < 2) {
            u16* O = z ? Kb : Qb;
            const float* bias = z ? bk : bq;
            // Tr as [ml 128][jl 64] stride 68
#pragma unroll
            for (int j = 0; j < 2; ++j) {
                int jl = wn * 32 + j * 16 + fm;
                float bb = bias[j0 + jl];
#pragma unroll
                for (int i = 0; i < 4; ++i) {
                    int mlb = wm * 64 + i * 16 + quad * 4;
#pragma unroll
                    for (int r = 0; r < 4; ++r)
                        Tr[(mlb + r) * 68 + jl] = f2bf(acc[i][j][r] + bb);
                }
            }
            __syncthreads();
#pragma unroll
            for (int i2 = 0; i2 < 4; ++i2) {
                int f = i2 * 2048 + t * 8;
                int ml = f >> 6, jl = f & 63;
                union { uint2 u2[2]; short8 s8; } uu;
                uu.u2[0] = *(const uint2*)(Tr + ml * 68 + jl);
                uu.u2[1] = *(const uint2*)(Tr + ml * 68 + jl + 4);
                *(short8*)(O + (size_t)(m0 + ml) * 1024 + j0 + jl) = uu.s8;
            }
        } else {
            // Tr as [jl 64][ml 128] stride 136
#pragma unroll
            for (int j = 0; j < 2; ++j) {
                int jl = wn * 32 + j * 16 + fm;
#pragma unroll
                for (int i = 0; i < 4; ++i) {
                    int mlb = wm * 64 + i * 16 + quad * 4;
                    uint2 pk;
                    pk.x = pkbf(acc[i][j][0], acc[i][j][1]);
                    pk.y = pkbf(acc[i][j][2], acc[i][j][3]);
                    *(uint2*)(Tr + jl * 136 + mlb) = pk;
                }
            }
            __syncthreads();
#pragma unroll
            for (int i2 = 0; i2 < 4; ++i2) {
                int f = i2 * 2048 + t * 8;
                int jl = f >> 7, ml = f & 127;
                union { uint2 u2[2]; short8 s8; } uu;
                uu.u2[0] = *(const uint2*)(Tr + jl * 136 + ml);
                uu.u2[1] = *(const uint2*)(Tr + jl * 136 + ml + 4);
                *(short8*)(PVt + (size_t)(j0 + jl) * PT + m0 + ml) = uu.s8;
            }
        }
        return;
    }

    // ================= posw path (r6 sin-chain, 8-iter halves) =================
    // Per-wave LDS stage: 8 iters x 264 u16 (2112 u16/wave, 8448 total).
    // [iter][(quad*16+fm)*4 + r] holds g=fm, p = iter*16 + quad*4 + r.
    u16* Wl = SH + w * 2112;

    const int n = grp * 8 + (rem - 3);
    const int n1b = *n1b_p, n1p = *n1p_p;
    const int hh = (n >= n1b) ? 1 : 0;
    const int p0 = hh ? n1p : 0;
    const int Ph = hh ? (PT - n1p) : n1p;   // 1024

    // n-box (block-uniform)
    float xmin = rois[n * 5 + 1], ymin = rois[n * 5 + 2];
    float xmax = rois[n * 5 + 3], ymax = rois[n * 5 + 4];
    float bw = xmax - xmin + 1.0f, bh = ymax - ymin + 1.0f;
    float cx = 0.5f * (xmin + xmax), cy = 0.5f * (ymin + ymax);

    const int jA = quad >> 1, trig = quad & 1;
    float cA   = (jA == 0) ? cx : cy;
    float invA = (jA == 0) ? (1.0f / bw) : (1.0f / bh);
    float lB   = (jA == 0) ? __logf(bw) : __logf(bh);
    float toff = trig ? 0.25f : 0.0f;

    // Wg b-fragments in registers; bias folded into acc init
    const int g_ = fm;
    short8 b1, b2;
    {
        const float* w1 = Wg_w + g_ * 64 + quad * 8;
        const float* w2 = Wg_w + g_ * 64 + 32 + quad * 8;
        unsigned* p1 = (unsigned*)&b1;
        unsigned* p2 = (unsigned*)&b2;
#pragma unroll
        for (int kk = 0; kk < 4; ++kk) {
            p1[kk] = pkbf(w1[2 * kk], w1[2 * kk + 1]);
            p2[kk] = pkbf(w2[2 * kk], w2[2 * kk + 1]);
        }
    }
    float wgb = Wg_b[g_];

    const float inv_em[8] = {1.0f, 0.4216965034f, 0.1778279410f, 0.0749894209f,
                             0.0316227766f, 0.0133352143f, 0.0056234133f, 0.0023713737f};
    const float REV = 15.91549431f;  // 100 / (2*pi)
    const int prange = Ph >> 2;      // p per wave (256)
    const int pb0 = w * prange;

    // software pipeline: prefetch PD one tile ahead
    float4 pd_c = PD[p0 + pb0 + fm];

    for (int half = 0; half < 2; ++half) {
#pragma unroll 2
        for (int pt8 = 0; pt8 < 8; ++pt8) {
            int pt = half * 8 + pt8;
            float4 pd_n;
            if (pt < 15) pd_n = PD[p0 + pb0 + pt * 16 + 16 + fm];
            float pc = (jA == 0) ? pd_c.x : pd_c.y;
            float lp = (jA == 0) ? pd_c.z : pd_c.w;
            float posA = __logf(fmaxf(fabsf(cA - pc) * invA, 0.001f));
            float posB = lp - lB;
            float br1 = posA * REV, br2 = posB * REV;
            float e1[8], e2[8];
#pragma unroll
            for (int k = 0; k < 8; ++k) {
                e1[k] = sin_rev(fmaf(br1, inv_em[k], toff));
                e2[k] = sin_rev(fmaf(br2, inv_em[k], toff));
            }
            short8 a1, a2;
            unsigned* pa1 = (unsigned*)&a1;
            unsigned* pa2 = (unsigned*)&a2;
#pragma unroll
            for (int kk = 0; kk < 4; ++kk) {
                pa1[kk] = pkbf(e1[2 * kk], e1[2 * kk + 1]);
                pa2[kk] = pkbf(e2[2 * kk], e2[2 * kk + 1]);
            }
            float4v acc = {wgb, wgb, wgb, wgb};
            acc = __builtin_amdgcn_mfma_f32_16x16x32_bf16(a1, b1, acc, 0, 0, 0);
            acc = __builtin_amdgcn_mfma_f32_16x16x32_bf16(a2, b2, acc, 0, 0, 0);

            float w0  = fmaxf(acc[0], 1e-6f);
            float w1v = fmaxf(acc[1], 1e-6f);
            float w2v = fmaxf(acc[2], 1e-6f);
            float w3v = fmaxf(acc[3], 1e-6f);
            uint2 wp; wp.x = pkbf(w0, w1v); wp.y = pkbf(w2v, w3v);
            *(uint2*)(Wl + pt8 * 264 + lane * 4) = wp;   // lane == quad*16+fm

            pd_c = pd_n;
        }
        // coalesced flush of this half: 16 lanes x 16B = 256B runs per g-row
        {
            const int p8 = (lane & 15) * 8;
            const int itq = p8 >> 4, q0 = (p8 >> 2) & 3;
            const int phh = half * 128;
#pragma unroll
            for (int s = 0; s < 4; ++s) {
                int gg = s * 4 + (lane >> 4);
                union { uint2 u2[2]; short8 s8; } uu;
                uu.u2[0] = *(const uint2*)(Wl + itq * 264 + (q0 * 16 + gg) * 4);
                uu.u2[1] = *(const uint2*)(Wl + itq * 264 + ((q0 + 1) * 16 + gg) * 4);
                *(short8*)(POSW + ((size_t)n * 16 + gg) * 1024 + pb0 + phh + p8) = uu.s8;
            }
        }
    }
}

// ---------------------------------------------------------------------------
// fused_rel v4: att^T = mfma(K,Q) + T14 reg-staging; LDS trimmed to 48 KB
// -> 3 blocks/CU (12 waves/CU):
//   - Q fragments loaded DIRECTLY from global (Qs eliminated; the swizzled
//     LDS read of chunk c equals a direct 16B load of chunk c).
//   - Ps single-buffered: wave w stages and reads ONLY rows w*16..w*16+15
//     (wave-private), so in-wave program order is the only needed ordering.
// K/V double-buffered; ONE __syncthreads per p-tile; POSW loads 2 tiles deep.
// ---------------------------------------------------------------------------
__global__ __launch_bounds__(256)
void fused_rel(const u16* __restrict__ Qb, const u16* __restrict__ Kb,
               const u16* __restrict__ POSW, const u16* __restrict__ PVt,
               const float* __restrict__ conv_b, float* __restrict__ OUT,
               const int* __restrict__ n1b_p, const int* __restrict__ n1p_p, int PT) {
    __shared__ __align__(16) u16 Ks[2][64 * 64];     // 16 KB
    __shared__ __align__(16) u16 Ps[64 * 64];        //  8 KB (wave-private rows)
    __shared__ __align__(16) u16 Vs[2][64 * 64];     // 16 KB
    __shared__ __align__(16) u16 Wt[4][16 * 64];     //  8 KB (wave-private rows)

    const int n0 = blockIdx.x * 64, g = blockIdx.y;
    const int n1b = *n1b_p, n1p = *n1p_p;
    const int hh = (n0 >= n1b) ? 1 : 0;
    const int p0 = hh ? n1p : 0;
    const int Ph = hh ? (PT - n1p) : n1p;
    const int t = threadIdx.x;
    const int w = t >> 6, lane = t & 63;
    const int lr = lane >> 3, lc = lane & 7, gch = lc ^ lr;
    const int fm = lane & 15, quad = lane >> 4;
    const int swz = fm & 7;
    const int nloc = w * 16 + fm;

    // per-lane element-offset bases for the two 16B chunks each lane moves
    const int row0 = w * 16 + lr, row1 = w * 16 + 8 + lr;
    const size_t kb0 = (size_t)(p0 + row0) * 1024 + g * 64 + gch * 8;
    const size_t kb1 = (size_t)(p0 + row1) * 1024 + g * 64 + gch * 8;
    const size_t vb0 = (size_t)(g * 64 + row0) * PT + p0 + gch * 8;
    const size_t vb1 = (size_t)(g * 64 + row1) * PT + p0 + gch * 8;
    const size_t pbs0 = ((size_t)(n0 + row0) * 16 + g) * 1024 + gch * 8;
    const size_t pbs1 = ((size_t)(n0 + row1) * 16 + g) * 1024 + gch * 8;
    const int d0 = (w * 16) * 64 + lane * 8;
    const int d1 = (w * 16 + 8) * 64 + lane * 8;

    // prologue: tile-0 K/V/P via regs; P(1) issued deep; Q frags direct.
    {
        uint4 ka = *(const uint4*)(Kb + kb0), kbv = *(const uint4*)(Kb + kb1);
        uint4 va = *(const uint4*)(PVt + vb0), vb = *(const uint4*)(PVt + vb1);
        uint4 pa = *(const uint4*)(POSW + pbs0), pbv = *(const uint4*)(POSW + pbs1);
        *(uint4*)(Ks[0] + d0) = ka;  *(uint4*)(Ks[0] + d1) = kbv;
        *(uint4*)(Vs[0] + d0) = va;  *(uint4*)(Vs[0] + d1) = vb;
        *(uint4*)(Ps + d0) = pa;     *(uint4*)(Ps + d1) = pbv;
    }
    uint4 prH0 = *(const uint4*)(POSW + pbs0 + 64);   // P(1)
    uint4 prH1 = *(const uint4*)(POSW + pbs1 + 64);
    short8 qf[2];
#pragma unroll
    for (int kd = 0; kd < 2; ++kd)
        qf[kd] = *(const short8*)(Qb + (size_t)(n0 + nloc) * 1024 + g * 64 + (kd * 4 + quad) * 8);

    float4v zero4 = {0.f, 0.f, 0.f, 0.f};
    float4v oacc[4];
#pragma unroll
    for (int ob = 0; ob < 4; ++ob) oacc[ob] = zero4;
    float rsum = 0.0f;

    __syncthreads();

    u16* wrow = Wt[w] + fm * 64;

    const int NPT = Ph >> 6;   // 16
    for (int pt = 0; pt < NPT; ++pt) {
        const int cur = pt & 1, nxt = cur ^ 1;
        const u16* ks_ = Ks[cur];
        const u16* vs_ = Vs[cur];
        const bool have1 = (pt + 1 < NPT), have2 = (pt + 2 < NPT);

        // issue-early: K/V(pt+1) and POSW(pt+2) -> regs
        uint4 kra, krb, vra, vrb, prN0, prN1;
        if (have1) {
            size_t o = (size_t)(pt + 1) * 65536;
            kra = *(const uint4*)(Kb + kb0 + o);
            krb = *(const uint4*)(Kb + kb1 + o);
            vra = *(const uint4*)(PVt + vb0 + (pt + 1) * 64);
            vrb = *(const uint4*)(PVt + vb1 + (pt + 1) * 64);
        }
        if (have2) {
            prN0 = *(const uint4*)(POSW + pbs0 + (pt + 2) * 64);
            prN1 = *(const uint4*)(POSW + pbs1 + (pt + 2) * 64);
        }

        // att^T = mfma(K, Q): C[p-row = quad*4+r][n-col = fm]
        float4v atc[4];
#pragma unroll
        for (int pi = 0; pi < 4; ++pi) atc[pi] = zero4;
#pragma unroll
        for (int kd = 0; kd < 2; ++kd) {
            int c = kd * 4 + quad;
#pragma unroll
            for (int pi = 0; pi < 4; ++pi) {
                int rp = pi * 16 + fm;
                short8 kf = *(const short8*)(ks_ + rp * 64 + ((c ^ swz) * 8));
                atc[pi] = __builtin_amdgcn_mfma_f32_16x16x32_bf16(kf, qf[kd], atc[pi], 0, 0, 0);
            }
        }

        // w-phase (register-resident, wave-local): lane's n = nloc,
        // p = pi*16 + quad*4 + r.
#pragma unroll
        for (int pi = 0; pi < 4; ++pi) {
            int co = ((pi * 2 + (quad >> 1)) ^ swz) * 8 + (quad & 1) * 4;  // u16 units
            uint2 pwp = *(const uint2*)(Ps + nloc * 64 + co);
            const u16* pww = (const u16*)&pwp;
            float wv0 = bf2f(pww[0]) * __expf(atc[pi][0] * 0.0625f);
            float wv1 = bf2f(pww[1]) * __expf(atc[pi][1] * 0.0625f);
            float wv2 = bf2f(pww[2]) * __expf(atc[pi][2] * 0.0625f);
            float wv3 = bf2f(pww[3]) * __expf(atc[pi][3] * 0.0625f);
            rsum += (wv0 + wv1) + (wv2 + wv3);
            uint2 wp; wp.x = pkbf(wv0, wv1); wp.y = pkbf(wv2, wv3);
            *(uint2*)(wrow + co) = wp;
        }

        // PV: out[n][o] += w[n,p] . V[o,p]; A-frag from wave-private Wt
#pragma unroll
        for (int m = 0; m < 2; ++m) {
            short8 af = *(const short8*)(wrow + (((m * 4 + quad) ^ swz) * 8));
#pragma unroll
            for (int ob = 0; ob < 4; ++ob) {
                int ro = ob * 16 + fm;
                short8 vf = *(const short8*)(vs_ + ro * 64 + (((m * 4 + quad) ^ swz) * 8));
                oacc[ob] = __builtin_amdgcn_mfma_f32_16x16x32_bf16(af, vf, oacc[ob], 0, 0, 0);
            }
        }

        // write-late: next-tile K/V into [nxt]; P(pt+1) into wave-private Ps
        // (already consumed this iter). vmcnt waits sit HERE.
        if (have1) {
            *(uint4*)(Ks[nxt] + d0) = kra;  *(uint4*)(Ks[nxt] + d1) = krb;
            *(uint4*)(Vs[nxt] + d0) = vra;  *(uint4*)(Vs[nxt] + d1) = vrb;
            *(uint4*)(Ps + d0) = prH0;      *(uint4*)(Ps + d1) = prH1;
            prH0 = prN0; prH1 = prN1;
        }

        __syncthreads();   // publishes K/V[nxt]; Ps/Wt are wave-private
    }

    // rsum: lane-local over its p-subset -> reduce across the 4 quads
    float s = rsum;
    s += __shfl_xor(s, 16, 64);
    s += __shfl_xor(s, 32, 64);
    // oacc rows are n = w*16 + quad*4 + r; sums live at lane (quad*4+r) (quad0)
    float inv[4];
#pragma unroll
    for (int r = 0; r < 4; ++r)
        inv[r] = 1.0f / __shfl(s, quad * 4 + r, 64);

    float bb[4];
#pragma unroll
    for (int ob = 0; ob < 4; ++ob) bb[ob] = conv_b[g * 64 + ob * 16 + fm];
#pragma unroll
    for (int ob = 0; ob < 4; ++ob)
#pragma unroll
        for (int r = 0; r < 4; ++r) {
            int nn = n0 + w * 16 + quad * 4 + r;
            OUT[(size_t)nn * 1024 + g * 64 + ob * 16 + fm] = oacc[ob][r] * inv[r] + bb[ob];
        }
}

extern "C" void kernel_launch(void* const* d_in, const int* in_sizes, int n_in,
                              void* d_out, int out_size, void* d_ws, size_t ws_size,
                              hipStream_t stream) {
    const float* rois   = (const float*)d_in[0];
    const float* prois  = (const float*)d_in[1];
    const float* bfeat  = (const float*)d_in[2];
    const float* pfeat  = (const float*)d_in[3];
    const float* Wg_w   = (const float*)d_in[4];
    const float* Wg_b   = (const float*)d_in[5];
    const float* Wq_w   = (const float*)d_in[6];
    const float* Wq_b   = (const float*)d_in[7];
    const float* Wk_w   = (const float*)d_in[8];
    const float* Wk_b   = (const float*)d_in[9];
    const float* conv_w = (const float*)d_in[10];
    const float* conv_b = (const float*)d_in[11];
    const int*   n1b    = (const int*)d_in[12];
    const int*   n1p    = (const int*)d_in[13];

    const int NT = in_sizes[2] / 1024;  // 2048
    const int PT = in_sizes[3] / 1024;  // 2048

    u16* Qb   = (u16*)d_ws;                          // [NT][1024]
    u16* Kb   = Qb + (size_t)NT * 1024;              // [PT][1024]
    u16* PVt  = Kb + (size_t)PT * 1024;              // [1024][PT]
    float4* PD = (float4*)(PVt + (size_t)1024 * PT); // [PT]
    u16* POSW = (u16*)(PD + PT);                     // [NT][16][1024]
    u16* Ab   = POSW + (size_t)NT * 16 * 1024;       // bf16 staging (proj inputs)
    u16* Pb   = Ab + (size_t)NT * 1024;
    u16* Wqb  = Pb + (size_t)PT * 1024;
    u16* Wkb  = Wqb + 1024 * 1024;
    u16* Cwb  = Wkb + 1024 * 1024;

    dim3 blk(256);
    int nf4 = NT * 1024 / 4, pf4 = PT * 1024 / 4, wf4 = 1024 * 1024 / 4;
    int tot = nf4 + pf4 + 3 * wf4 + PT;
    cvt_all<<<dim3((tot + 255) / 256), blk, 0, stream>>>(
        bfeat, pfeat, Wq_w, Wk_w, conv_w, prois, Ab, Pb, Wqb, Wkb, Cwb, PD,
        nf4, pf4, wf4, PT);

    // 768 proj blocks + NT posw blocks, interleaved 3:8 per group of 11.
    proj_posw<<<dim3(256 * 11), blk, 0, stream>>>(Ab, Pb, Wqb, Wkb, Cwb,
                                                  Wq_b, Wk_b, Qb, Kb, PVt,
                                                  rois, PD, Wg_w, Wg_b, POSW,
                                                  n1b, n1p, PT);
    fused_rel<<<dim3(NT / 64, 16), blk, 0, stream>>>(Qb, Kb, POSW, PVt, conv_b,
                                                     (float*)d_out, n1b, n1p, PT);
}

// Round 9
// 171.454 us; speedup vs baseline: 1.0090x; 1.0090x over previous
//
#include <hip/hip_runtime.h>

typedef unsigned short u16;
using short8  = __attribute__((ext_vector_type(8))) short;
using float4v = __attribute__((ext_vector_type(4))) float;

__device__ __forceinline__ u16 f2bf(float f) {
    union { float f; unsigned u; } v; v.f = f;
    unsigned r = (v.u + 0x7fff + ((v.u >> 16) & 1)) >> 16;
    return (u16)r;
}
__device__ __forceinline__ float bf2f(u16 h) {
    union { unsigned u; float f; } v; v.u = ((unsigned)h) << 16; return v.f;
}
// HW packed f32x2 -> bf16x2 (lo in low 16 bits). CDNA3+/gfx950.
__device__ __forceinline__ unsigned pkbf(float lo, float hi) {
    unsigned d;
    asm("v_cvt_pk_bf16_f32 %0, %1, %2" : "=v"(d) : "v"(lo), "v"(hi));
    return d;
}
// sin(2*pi*r): v_fract then hardware v_sin (input in revolutions).
__device__ __forceinline__ float sin_rev(float r) {
    float f, s;
    asm("v_fract_f32 %0, %1" : "=v"(f) : "v"(r));
    asm("v_sin_f32 %0, %1" : "=v"(s) : "v"(f));
    return s;
}
__device__ __forceinline__ void dma16(const void* g, void* l) {
    __builtin_amdgcn_global_load_lds((const __attribute__((address_space(1))) void*)g,
                                     (__attribute__((address_space(3))) void*)l, 16, 0, 0);
}

// ---------------------------------------------------------------------------
// merged f32 -> bf16 bulk convert for five tensors + PD precompute
// ---------------------------------------------------------------------------
__device__ __forceinline__ void cvt4(const float* __restrict__ s, u16* __restrict__ o, int i) {
    float4 v = ((const float4*)s)[i];
    uint2 r; r.x = pkbf(v.x, v.y); r.y = pkbf(v.z, v.w);
    ((uint2*)o)[i] = r;
}

__global__ __launch_bounds__(256)
void cvt_all(const float* __restrict__ s0, const float* __restrict__ s1,
             const float* __restrict__ s2, const float* __restrict__ s3,
             const float* __restrict__ s4, const float* __restrict__ prois,
             u16* __restrict__ o0, u16* __restrict__ o1, u16* __restrict__ o2,
             u16* __restrict__ o3, u16* __restrict__ o4, float4* __restrict__ PD,
             int na4, int nb4, int nw4, int PT) {
    int i = blockIdx.x * 256 + threadIdx.x;
    if (i < na4) { cvt4(s0, o0, i); return; }
    i -= na4;
    if (i < nb4) { cvt4(s1, o1, i); return; }
    i -= nb4;
    if (i < nw4) { cvt4(s2, o2, i); return; }
    i -= nw4;
    if (i < nw4) { cvt4(s3, o3, i); return; }
    i -= nw4;
    if (i < nw4) { cvt4(s4, o4, i); return; }
    i -= nw4;
    if (i < PT) {
        const float* pr = prois + (size_t)i * 5;
        float pxmin = pr[1], pymin = pr[2], pxmax = pr[3], pymax = pr[4];
        PD[i] = make_float4(0.5f * (pxmin + pxmax), 0.5f * (pymin + pymax),
                            __logf(pxmax - pxmin + 1.0f), __logf(pymax - pymin + 1.0f));
    }
}

// ---------------------------------------------------------------------------
// proj_posw: fused proj GEMMs (MFMA-bound) + posw embedding (VALU-bound),
// interleaved 3:8 per group of 11 blocks. LDS 48 KB.
//   proj:  T14 reg-staged K-loop -- double-buffered As/Ws, global->reg loads
//          issued one K-step ahead, ds_write after the MFMAs, ONE barrier per
//          K-step (lgkm-only; no vmcnt(0) drain).  Tr epilogue aliases As.
//          (buffer selection via runtime offset arith -- pointer-array init
//           from LDS is rejected by the gfx950 backend.)
//   posw:  r3/r6 sin-chain, 16-iter per-wave stage, 512B-run flush.
// ---------------------------------------------------------------------------
__global__ __launch_bounds__(256)
void proj_posw(const u16* __restrict__ Ab, const u16* __restrict__ Pb,
               const u16* __restrict__ Wqb, const u16* __restrict__ Wkb,
               const u16* __restrict__ Cwb, const float* __restrict__ bq,
               const float* __restrict__ bk, u16* __restrict__ Qb,
               u16* __restrict__ Kb, u16* __restrict__ PVt,
               const float* __restrict__ rois, const float4* __restrict__ PD,
               const float* __restrict__ Wg_w, const float* __restrict__ Wg_b,
               u16* __restrict__ POSW, const int* __restrict__ n1b_p,
               const int* __restrict__ n1p_p, int PT) {
    __shared__ __align__(16) u16 SH[24576];   // 48 KB

    const int grp = blockIdx.x / 11, rem = blockIdx.x % 11;
    const int t = threadIdx.x;
    const int w = t >> 6, lane = t & 63;
    const int fm = lane & 15, quad = lane >> 4;

    if (rem < 3) {
        // ================= proj path (T14 reg-staged) =================
        // LDS map: A-buf0 @0, A-buf1 @8192, W-buf0 @16384, W-buf1 @20480.
        u16* Tr = SH;                             // aliases A-bufs after k-loop
        const int pb = grp * 3 + rem;
        const int z = pb >> 8;
        const int m0 = ((pb >> 4) & 15) * 128, j0 = (pb & 15) * 64;
        const u16* A = (z == 0) ? Ab : Pb;
        const u16* W = (z == 0) ? Wqb : (z == 1 ? Wkb : Cwb);
        const int wm = w >> 1, wn = w & 1;
        const int lr = lane >> 3, lc = lane & 7, gch = lc ^ lr;

        // per-lane global/LDS addresses for the staged chunks
        size_t ga[4], gw[2];
        int da[4], dw[2];
#pragma unroll
        for (int i = 0; i < 4; ++i) {
            ga[i] = (size_t)(m0 + w * 32 + i * 8 + lr) * 1024 + gch * 8;
            da[i] = (w * 32 + i * 8) * 64 + lane * 8;
        }
#pragma unroll
        for (int i = 0; i < 2; ++i) {
            gw[i] = (size_t)(j0 + w * 16 + i * 8 + lr) * 1024 + gch * 8;
            dw[i] = 16384 + (w * 16 + i * 8) * 64 + lane * 8;
        }

        float4v zero4 = {0.f, 0.f, 0.f, 0.f};
        float4v acc[4][2];
#pragma unroll
        for (int i = 0; i < 4; ++i) { acc[i][0] = zero4; acc[i][1] = zero4; }

        // prologue: tile 0 -> regs -> LDS buf0
        {
            uint4 ar[4], wr[2];
#pragma unroll
            for (int i = 0; i < 4; ++i) ar[i] = *(const uint4*)(A + ga[i]);
#pragma unroll
            for (int i = 0; i < 2; ++i) wr[i] = *(const uint4*)(W + gw[i]);
#pragma unroll
            for (int i = 0; i < 4; ++i) *(uint4*)(SH + da[i]) = ar[i];
#pragma unroll
            for (int i = 0; i < 2; ++i) *(uint4*)(SH + dw[i]) = wr[i];
        }
        __syncthreads();

        for (int kt = 0; kt < 16; ++kt) {
            const int cur = kt & 1, nxt = cur ^ 1;
            const int aCur = cur * 8192, wCur = cur * 4096;
            const int aNxt = nxt * 8192, wNxt = nxt * 4096;
            const bool more = kt < 15;
            uint4 ar[4], wr[2];
            if (more) {
                const size_t k1 = (size_t)(kt + 1) * 64;
#pragma unroll
                for (int i = 0; i < 4; ++i) ar[i] = *(const uint4*)(A + ga[i] + k1);
#pragma unroll
                for (int i = 0; i < 2; ++i) wr[i] = *(const uint4*)(W + gw[i] + k1);
            }
            const u16* As = SH + aCur;
            const u16* Ws = SH + 16384 + wCur;
#pragma unroll
            for (int ks = 0; ks < 2; ++ks) {
                int c = ks * 4 + quad;
                short8 af[4], bf[2];
#pragma unroll
                for (int i = 0; i < 4; ++i) {
                    int ra = wm * 64 + i * 16 + fm;
                    af[i] = *(const short8*)(As + ra * 64 + ((c ^ (ra & 7)) * 8));
                }
#pragma unroll
                for (int j = 0; j < 2; ++j) {
                    int rb = wn * 32 + j * 16 + fm;
                    bf[j] = *(const short8*)(Ws + rb * 64 + ((c ^ (rb & 7)) * 8));
                }
#pragma unroll
                for (int i = 0; i < 4; ++i)
#pragma unroll
                    for (int j = 0; j < 2; ++j)
                        acc[i][j] = __builtin_amdgcn_mfma_f32_16x16x32_bf16(af[i], bf[j], acc[i][j], 0, 0, 0);
            }
            if (more) {
#pragma unroll
                for (int i = 0; i < 4; ++i) *(uint4*)(SH + aNxt + da[i]) = ar[i];
#pragma unroll
                for (int i = 0; i < 2; ++i) *(uint4*)(SH + wNxt + dw[i]) = wr[i];
            }
            __syncthreads();   // publishes buf[nxt]; lgkm-only (no dma16)
        }
        // k-loop ended with a barrier: A/W bufs dead, Tr (alias) safe to write.

        if (z < 2) {
            u16* O = z ? Kb : Qb;
            const float* bias = z ? bk : bq;
            // Tr as [ml 128][jl 64] stride 68
#pragma unroll
            for (int j = 0; j < 2; ++j) {
                int jl = wn * 32 + j * 16 + fm;
                float bb = bias[j0 + jl];
#pragma unroll
                for (int i = 0; i < 4; ++i) {
                    int mlb = wm * 64 + i * 16 + quad * 4;
#pragma unroll
                    for (int r = 0; r < 4; ++r)
                        Tr[(mlb + r) * 68 + jl] = f2bf(acc[i][j][r] + bb);
                }
            }
            __syncthreads();
#pragma unroll
            for (int i2 = 0; i2 < 4; ++i2) {
                int f = i2 * 2048 + t * 8;
                int ml = f >> 6, jl = f & 63;
                union { uint2 u2[2]; short8 s8; } uu;
                uu.u2[0] = *(const uint2*)(Tr + ml * 68 + jl);
                uu.u2[1] = *(const uint2*)(Tr + ml * 68 + jl + 4);
                *(short8*)(O + (size_t)(m0 + ml) * 1024 + j0 + jl) = uu.s8;
            }
        } else {
            // Tr as [jl 64][ml 128] stride 136
#pragma unroll
            for (int j = 0; j < 2; ++j) {
                int jl = wn * 32 + j * 16 + fm;
#pragma unroll
                for (int i = 0; i < 4; ++i) {
                    int mlb = wm * 64 + i * 16 + quad * 4;
                    uint2 pk;
                    pk.x = pkbf(acc[i][j][0], acc[i][j][1]);
                    pk.y = pkbf(acc[i][j][2], acc[i][j][3]);
                    *(uint2*)(Tr + jl * 136 + mlb) = pk;
                }
            }
            __syncthreads();
#pragma unroll
            for (int i2 = 0; i2 < 4; ++i2) {
                int f = i2 * 2048 + t * 8;
                int jl = f >> 7, ml = f & 127;
                union { uint2 u2[2]; short8 s8; } uu;
                uu.u2[0] = *(const uint2*)(Tr + jl * 136 + ml);
                uu.u2[1] = *(const uint2*)(Tr + jl * 136 + ml + 4);
                *(short8*)(PVt + (size_t)(j0 + jl) * PT + m0 + ml) = uu.s8;
            }
        }
        return;
    }

    // ================= posw path (r6 sin-chain, 16-iter stage) =================
    // Per-wave LDS stage: 16 iters x 264 u16 (4224 u16/wave, 16896 total).
    // [iter][(quad*16+fm)*4 + r] holds g=fm, p = iter*16 + quad*4 + r.
    u16* Wl = SH + w * 4224;

    const int n = grp * 8 + (rem - 3);
    const int n1b = *n1b_p, n1p = *n1p_p;
    const int hh = (n >= n1b) ? 1 : 0;
    const int p0 = hh ? n1p : 0;
    const int Ph = hh ? (PT - n1p) : n1p;   // 1024

    // n-box (block-uniform)
    float xmin = rois[n * 5 + 1], ymin = rois[n * 5 + 2];
    float xmax = rois[n * 5 + 3], ymax = rois[n * 5 + 4];
    float bw = xmax - xmin + 1.0f, bh = ymax - ymin + 1.0f;
    float cx = 0.5f * (xmin + xmax), cy = 0.5f * (ymin + ymax);

    const int jA = quad >> 1, trig = quad & 1;
    float cA   = (jA == 0) ? cx : cy;
    float invA = (jA == 0) ? (1.0f / bw) : (1.0f / bh);
    float lB   = (jA == 0) ? __logf(bw) : __logf(bh);
    float toff = trig ? 0.25f : 0.0f;

    // Wg b-fragments in registers; bias folded into acc init
    const int g_ = fm;
    short8 b1, b2;
    {
        const float* w1 = Wg_w + g_ * 64 + quad * 8;
        const float* w2 = Wg_w + g_ * 64 + 32 + quad * 8;
        unsigned* p1 = (unsigned*)&b1;
        unsigned* p2 = (unsigned*)&b2;
#pragma unroll
        for (int kk = 0; kk < 4; ++kk) {
            p1[kk] = pkbf(w1[2 * kk], w1[2 * kk + 1]);
            p2[kk] = pkbf(w2[2 * kk], w2[2 * kk + 1]);
        }
    }
    float wgb = Wg_b[g_];

    const float inv_em[8] = {1.0f, 0.4216965034f, 0.1778279410f, 0.0749894209f,
                             0.0316227766f, 0.0133352143f, 0.0056234133f, 0.0023713737f};
    const float REV = 15.91549431f;  // 100 / (2*pi)
    const int prange = Ph >> 2;      // p per wave (256)
    const int pb0 = w * prange;

    // software pipeline: prefetch PD one tile ahead
    float4 pd_c = PD[p0 + pb0 + fm];

#pragma unroll 2
    for (int pt = 0; pt < 16; ++pt) {
        float4 pd_n;
        if (pt < 15) pd_n = PD[p0 + pb0 + pt * 16 + 16 + fm];
        float pc = (jA == 0) ? pd_c.x : pd_c.y;
        float lp = (jA == 0) ? pd_c.z : pd_c.w;
        float posA = __logf(fmaxf(fabsf(cA - pc) * invA, 0.001f));
        float posB = lp - lB;
        float br1 = posA * REV, br2 = posB * REV;
        float e1[8], e2[8];
#pragma unroll
        for (int k = 0; k < 8; ++k) {
            e1[k] = sin_rev(fmaf(br1, inv_em[k], toff));
            e2[k] = sin_rev(fmaf(br2, inv_em[k], toff));
        }
        short8 a1, a2;
        unsigned* pa1 = (unsigned*)&a1;
        unsigned* pa2 = (unsigned*)&a2;
#pragma unroll
        for (int kk = 0; kk < 4; ++kk) {
            pa1[kk] = pkbf(e1[2 * kk], e1[2 * kk + 1]);
            pa2[kk] = pkbf(e2[2 * kk], e2[2 * kk + 1]);
        }
        float4v acc = {wgb, wgb, wgb, wgb};
        acc = __builtin_amdgcn_mfma_f32_16x16x32_bf16(a1, b1, acc, 0, 0, 0);
        acc = __builtin_amdgcn_mfma_f32_16x16x32_bf16(a2, b2, acc, 0, 0, 0);

        float w0  = fmaxf(acc[0], 1e-6f);
        float w1v = fmaxf(acc[1], 1e-6f);
        float w2v = fmaxf(acc[2], 1e-6f);
        float w3v = fmaxf(acc[3], 1e-6f);
        uint2 wp; wp.x = pkbf(w0, w1v); wp.y = pkbf(w2v, w3v);
        *(uint2*)(Wl + pt * 264 + lane * 4) = wp;   // lane == quad*16+fm

        pd_c = pd_n;
    }

    // coalesced flush: per sub-iter, 2 g-rows x 32 lanes x 16B = full 512B rows
    const int p8 = (lane & 31) * 8;      // p start within this wave's 256
    const int halfg = lane >> 5;         // 0/1
    const int itq = p8 >> 4;             // source iter
    const int q0 = (p8 >> 2) & 3;        // 0 or 2
#pragma unroll
    for (int s = 0; s < 8; ++s) {
        int gg = s * 2 + halfg;
        union { uint2 u2[2]; short8 s8; } uu;
        uu.u2[0] = *(const uint2*)(Wl + itq * 264 + (q0 * 16 + gg) * 4);
        uu.u2[1] = *(const uint2*)(Wl + itq * 264 + ((q0 + 1) * 16 + gg) * 4);
        *(short8*)(POSW + ((size_t)n * 16 + gg) * 1024 + pb0 + p8) = uu.s8;
    }
}

// ---------------------------------------------------------------------------
// fused_rel (r6 v3): att^T = mfma(K,Q) (lane-local w-phase) + T14 reg-staging.
// In-loop transport is global_load->VGPR + late ds_write (NO dma16 in loop),
// so barriers need only lgkmcnt: K/V waits retire 1 tile after issue (L2),
// POSW waits retire 2 tiles after issue (HBM).  ONE __syncthreads per p-tile.
// Grid (NT/64, 16) = 512 blocks; LDS 64 KB -> 2 blocks/CU.
// ---------------------------------------------------------------------------
__global__ __launch_bounds__(256)
void fused_rel(const u16* __restrict__ Qb, const u16* __restrict__ Kb,
               const u16* __restrict__ POSW, const u16* __restrict__ PVt,
               const float* __restrict__ conv_b, float* __restrict__ OUT,
               const int* __restrict__ n1b_p, const int* __restrict__ n1p_p, int PT) {
    __shared__ __align__(16) u16 Qs[64 * 64];        // 8 KB
    __shared__ __align__(16) u16 Ks[2][64 * 64];     // 16 KB
    __shared__ __align__(16) u16 Ps[2][64 * 64];     // 16 KB
    __shared__ __align__(16) u16 Vs[2][64 * 64];     // 16 KB
    __shared__ __align__(16) u16 Wt[4][16 * 64];     // 8 KB (wave-private rows)

    const int n0 = blockIdx.x * 64, g = blockIdx.y;
    const int n1b = *n1b_p, n1p = *n1p_p;
    const int hh = (n0 >= n1b) ? 1 : 0;
    const int p0 = hh ? n1p : 0;
    const int Ph = hh ? (PT - n1p) : n1p;
    const int t = threadIdx.x;
    const int w = t >> 6, lane = t & 63;
    const int lr = lane >> 3, lc = lane & 7, gch = lc ^ lr;
    const int fm = lane & 15, quad = lane >> 4;
    const int swz = fm & 7;

    // per-lane element-offset bases for the two 16B chunks each lane moves
    const int row0 = w * 16 + lr, row1 = w * 16 + 8 + lr;
    const size_t kb0 = (size_t)(p0 + row0) * 1024 + g * 64 + gch * 8;
    const size_t kb1 = (size_t)(p0 + row1) * 1024 + g * 64 + gch * 8;
    const size_t vb0 = (size_t)(g * 64 + row0) * PT + p0 + gch * 8;
    const size_t vb1 = (size_t)(g * 64 + row1) * PT + p0 + gch * 8;
    const size_t pbs0 = ((size_t)(n0 + row0) * 16 + g) * 1024 + gch * 8;
    const size_t pbs1 = ((size_t)(n0 + row1) * 16 + g) * 1024 + gch * 8;
    const int d0 = (w * 16) * 64 + lane * 8;
    const int d1 = (w * 16 + 8) * 64 + lane * 8;

    // prologue: Q via dma16 (drained once at prologue barrier); tile 0 K/V/P
    // via regs; P(1) issued deep.
    dma16(Qb + (size_t)(n0 + row0) * 1024 + g * 64 + gch * 8, Qs + d0);
    dma16(Qb + (size_t)(n0 + row1) * 1024 + g * 64 + gch * 8, Qs + d1);
    {
        uint4 ka = *(const uint4*)(Kb + kb0), kbv = *(const uint4*)(Kb + kb1);
        uint4 va = *(const uint4*)(PVt + vb0), vb = *(const uint4*)(PVt + vb1);
        uint4 pa = *(const uint4*)(POSW + pbs0), pbv = *(const uint4*)(POSW + pbs1);
        *(uint4*)(Ks[0] + d0) = ka;  *(uint4*)(Ks[0] + d1) = kbv;
        *(uint4*)(Vs[0] + d0) = va;  *(uint4*)(Vs[0] + d1) = vb;
        *(uint4*)(Ps[0] + d0) = pa;  *(uint4*)(Ps[0] + d1) = pbv;
    }
    uint4 prH0 = *(const uint4*)(POSW + pbs0 + 64);   // P(1)
    uint4 prH1 = *(const uint4*)(POSW + pbs1 + 64);

    float4v zero4 = {0.f, 0.f, 0.f, 0.f};
    float4v oacc[4];
#pragma unroll
    for (int ob = 0; ob < 4; ++ob) oacc[ob] = zero4;
    float rsum = 0.0f;

    __syncthreads();

    const int nloc = w * 16 + fm;
    // hoist Q fragments (B-operand rows = n); Qs stable from here on
    short8 qf[2];
#pragma unroll
    for (int kd = 0; kd < 2; ++kd) {
        int c = kd * 4 + quad;
        qf[kd] = *(const short8*)(Qs + nloc * 64 + ((c ^ swz) * 8));
    }
    u16* wrow = Wt[w] + fm * 64;

    const int NPT = Ph >> 6;   // 16
    for (int pt = 0; pt < NPT; ++pt) {
        const int cur = pt & 1, nxt = cur ^ 1;
        const u16* ks_ = Ks[cur];
        const u16* ps_ = Ps[cur];
        const u16* vs_ = Vs[cur];
        const bool have1 = (pt + 1 < NPT), have2 = (pt + 2 < NPT);

        // issue-early: K/V(pt+1) and POSW(pt+2) -> regs
        uint4 kra, krb, vra, vrb, prN0, prN1;
        if (have1) {
            size_t o = (size_t)(pt + 1) * 65536;
            kra = *(const uint4*)(Kb + kb0 + o);
            krb = *(const uint4*)(Kb + kb1 + o);
            vra = *(const uint4*)(PVt + vb0 + (pt + 1) * 64);
            vrb = *(const uint4*)(PVt + vb1 + (pt + 1) * 64);
        }
        if (have2) {
            prN0 = *(const uint4*)(POSW + pbs0 + (pt + 2) * 64);
            prN1 = *(const uint4*)(POSW + pbs1 + (pt + 2) * 64);
        }

        // att^T = mfma(K, Q): C[p-row = quad*4+r][n-col = fm]
        float4v atc[4];
#pragma unroll
        for (int pi = 0; pi < 4; ++pi) atc[pi] = zero4;
#pragma unroll
        for (int kd = 0; kd < 2; ++kd) {
            int c = kd * 4 + quad;
#pragma unroll
            for (int pi = 0; pi < 4; ++pi) {
                int rp = pi * 16 + fm;
                short8 kf = *(const short8*)(ks_ + rp * 64 + ((c ^ swz) * 8));
                atc[pi] = __builtin_amdgcn_mfma_f32_16x16x32_bf16(kf, qf[kd], atc[pi], 0, 0, 0);
            }
        }

        // w-phase (register-resident, wave-local): lane's n = nloc,
        // p = pi*16 + quad*4 + r.
#pragma unroll
        for (int pi = 0; pi < 4; ++pi) {
            int co = ((pi * 2 + (quad >> 1)) ^ swz) * 8 + (quad & 1) * 4;  // u16 units
            uint2 pwp = *(const uint2*)(ps_ + nloc * 64 + co);
            const u16* pww = (const u16*)&pwp;
            float wv0 = bf2f(pww[0]) * __expf(atc[pi][0] * 0.0625f);
            float wv1 = bf2f(pww[1]) * __expf(atc[pi][1] * 0.0625f);
            float wv2 = bf2f(pww[2]) * __expf(atc[pi][2] * 0.0625f);
            float wv3 = bf2f(pww[3]) * __expf(atc[pi][3] * 0.0625f);
            rsum += (wv0 + wv1) + (wv2 + wv3);
            uint2 wp; wp.x = pkbf(wv0, wv1); wp.y = pkbf(wv2, wv3);
            *(uint2*)(wrow + co) = wp;
        }

        // PV: out[n][o] += w[n,p] . V[o,p]; A-frag from wave-private Wt
#pragma unroll
        for (int m = 0; m < 2; ++m) {
            short8 af = *(const short8*)(wrow + (((m * 4 + quad) ^ swz) * 8));
#pragma unroll
            for (int ob = 0; ob < 4; ++ob) {
                int ro = ob * 16 + fm;
                short8 vf = *(const short8*)(vs_ + ro * 64 + (((m * 4 + quad) ^ swz) * 8));
                oacc[ob] = __builtin_amdgcn_mfma_f32_16x16x32_bf16(af, vf, oacc[ob], 0, 0, 0);
            }
        }

        // write-late: next-tile data into [nxt]; vmcnt waits sit HERE, with
        // K/V aged ~1 compute phase and POSW aged >= 1 full tile.
        if (have1) {
            *(uint4*)(Ks[nxt] + d0) = kra;  *(uint4*)(Ks[nxt] + d1) = krb;
            *(uint4*)(Vs[nxt] + d0) = vra;  *(uint4*)(Vs[nxt] + d1) = vrb;
            *(uint4*)(Ps[nxt] + d0) = prH0; *(uint4*)(Ps[nxt] + d1) = prH1;
            prH0 = prN0; prH1 = prN1;
        }

        __syncthreads();   // lgkm drain publishes [nxt]; no dma16 in flight
    }

    // rsum: lane-local over its p-subset -> reduce across the 4 quads
    float s = rsum;
    s += __shfl_xor(s, 16, 64);
    s += __shfl_xor(s, 32, 64);
    // oacc rows are n = w*16 + quad*4 + r; sums live at lane (quad*4+r) (quad0)
    float inv[4];
#pragma unroll
    for (int r = 0; r < 4; ++r)
        inv[r] = 1.0f / __shfl(s, quad * 4 + r, 64);

    float bb[4];
#pragma unroll
    for (int ob = 0; ob < 4; ++ob) bb[ob] = conv_b[g * 64 + ob * 16 + fm];
#pragma unroll
    for (int ob = 0; ob < 4; ++ob)
#pragma unroll
        for (int r = 0; r < 4; ++r) {
            int nn = n0 + w * 16 + quad * 4 + r;
            OUT[(size_t)nn * 1024 + g * 64 + ob * 16 + fm] = oacc[ob][r] * inv[r] + bb[ob];
        }
}

extern "C" void kernel_launch(void* const* d_in, const int* in_sizes, int n_in,
                              void* d_out, int out_size, void* d_ws, size_t ws_size,
                              hipStream_t stream) {
    const float* rois   = (const float*)d_in[0];
    const float* prois  = (const float*)d_in[1];
    const float* bfeat  = (const float*)d_in[2];
    const float* pfeat  = (const float*)d_in[3];
    const float* Wg_w   = (const float*)d_in[4];
    const float* Wg_b   = (const float*)d_in[5];
    const float* Wq_w   = (const float*)d_in[6];
    const float* Wq_b   = (const float*)d_in[7];
    const float* Wk_w   = (const float*)d_in[8];
    const float* Wk_b   = (const float*)d_in[9];
    const float* conv_w = (const float*)d_in[10];
    const float* conv_b = (const float*)d_in[11];
    const int*   n1b    = (const int*)d_in[12];
    const int*   n1p    = (const int*)d_in[13];

    const int NT = in_sizes[2] / 1024;  // 2048
    const int PT = in_sizes[3] / 1024;  // 2048

    u16* Qb   = (u16*)d_ws;                          // [NT][1024]
    u16* Kb   = Qb + (size_t)NT * 1024;              // [PT][1024]
    u16* PVt  = Kb + (size_t)PT * 1024;              // [1024][PT]
    float4* PD = (float4*)(PVt + (size_t)1024 * PT); // [PT]
    u16* POSW = (u16*)(PD + PT);                     // [NT][16][1024]
    u16* Ab   = POSW + (size_t)NT * 16 * 1024;       // bf16 staging (proj inputs)
    u16* Pb   = Ab + (size_t)NT * 1024;
    u16* Wqb  = Pb + (size_t)PT * 1024;
    u16* Wkb  = Wqb + 1024 * 1024;
    u16* Cwb  = Wkb + 1024 * 1024;

    dim3 blk(256);
    int nf4 = NT * 1024 / 4, pf4 = PT * 1024 / 4, wf4 = 1024 * 1024 / 4;
    int tot = nf4 + pf4 + 3 * wf4 + PT;
    cvt_all<<<dim3((tot + 255) / 256), blk, 0, stream>>>(
        bfeat, pfeat, Wq_w, Wk_w, conv_w, prois, Ab, Pb, Wqb, Wkb, Cwb, PD,
        nf4, pf4, wf4, PT);

    // 768 proj blocks + NT posw blocks, interleaved 3:8 per group of 11.
    proj_posw<<<dim3(256 * 11), blk, 0, stream>>>(Ab, Pb, Wqb, Wkb, Cwb,
                                                  Wq_b, Wk_b, Qb, Kb, PVt,
                                                  rois, PD, Wg_w, Wg_b, POSW,
                                                  n1b, n1p, PT);
    fused_rel<<<dim3(NT / 64, 16), blk, 0, stream>>>(Qb, Kb, POSW, PVt, conv_b,
                                                     (float*)d_out, n1b, n1p, PT);
}

// Round 10
// 168.327 us; speedup vs baseline: 1.0277x; 1.0186x over previous
//
#include <hip/hip_runtime.h>

typedef unsigned short u16;
using short8  = __attribute__((ext_vector_type(8))) short;
using float4v = __attribute__((ext_vector_type(4))) float;

__device__ __forceinline__ u16 f2bf(float f) {
    union { float f; unsigned u; } v; v.f = f;
    unsigned r = (v.u + 0x7fff + ((v.u >> 16) & 1)) >> 16;
    return (u16)r;
}
__device__ __forceinline__ float bf2f(u16 h) {
    union { unsigned u; float f; } v; v.u = ((unsigned)h) << 16; return v.f;
}
// HW packed f32x2 -> bf16x2 (lo in low 16 bits). CDNA3+/gfx950.
__device__ __forceinline__ unsigned pkbf(float lo, float hi) {
    unsigned d;
    asm("v_cvt_pk_bf16_f32 %0, %1, %2" : "=v"(d) : "v"(lo), "v"(hi));
    return d;
}
// sin(2*pi*r): v_fract then hardware v_sin (input in revolutions).
__device__ __forceinline__ float sin_rev(float r) {
    float f, s;
    asm("v_fract_f32 %0, %1" : "=v"(f) : "v"(r));
    asm("v_sin_f32 %0, %1" : "=v"(s) : "v"(f));
    return s;
}
__device__ __forceinline__ void dma16(const void* g, void* l) {
    __builtin_amdgcn_global_load_lds((const __attribute__((address_space(1))) void*)g,
                                     (__attribute__((address_space(3))) void*)l, 16, 0, 0);
}

// ---------------------------------------------------------------------------
// merged f32 -> bf16 bulk convert for five tensors + PD precompute
// ---------------------------------------------------------------------------
__device__ __forceinline__ void cvt4(const float* __restrict__ s, u16* __restrict__ o, int i) {
    float4 v = ((const float4*)s)[i];
    uint2 r; r.x = pkbf(v.x, v.y); r.y = pkbf(v.z, v.w);
    ((uint2*)o)[i] = r;
}

__global__ __launch_bounds__(256)
void cvt_all(const float* __restrict__ s0, const float* __restrict__ s1,
             const float* __restrict__ s2, const float* __restrict__ s3,
             const float* __restrict__ s4, const float* __restrict__ prois,
             u16* __restrict__ o0, u16* __restrict__ o1, u16* __restrict__ o2,
             u16* __restrict__ o3, u16* __restrict__ o4, float4* __restrict__ PD,
             int na4, int nb4, int nw4, int PT) {
    int i = blockIdx.x * 256 + threadIdx.x;
    if (i < na4) { cvt4(s0, o0, i); return; }
    i -= na4;
    if (i < nb4) { cvt4(s1, o1, i); return; }
    i -= nb4;
    if (i < nw4) { cvt4(s2, o2, i); return; }
    i -= nw4;
    if (i < nw4) { cvt4(s3, o3, i); return; }
    i -= nw4;
    if (i < nw4) { cvt4(s4, o4, i); return; }
    i -= nw4;
    if (i < PT) {
        const float* pr = prois + (size_t)i * 5;
        float pxmin = pr[1], pymin = pr[2], pxmax = pr[3], pymax = pr[4];
        PD[i] = make_float4(0.5f * (pxmin + pxmax), 0.5f * (pymin + pymax),
                            __logf(pxmax - pxmin + 1.0f), __logf(pymax - pymin + 1.0f));
    }
}

// ---------------------------------------------------------------------------
// proj_posw: fused proj GEMMs (MFMA-bound) + posw embedding (VALU-bound),
// interleaved 3:8 per group of 11 blocks. LDS 33 KB (Tr aliases As/Ws).
// posw = r3's proven sin-chain version.  [r6 best state: 52.5 us here]
// ---------------------------------------------------------------------------
__global__ __launch_bounds__(256)
void proj_posw(const u16* __restrict__ Ab, const u16* __restrict__ Pb,
               const u16* __restrict__ Wqb, const u16* __restrict__ Wkb,
               const u16* __restrict__ Cwb, const float* __restrict__ bq,
               const float* __restrict__ bk, u16* __restrict__ Qb,
               u16* __restrict__ Kb, u16* __restrict__ PVt,
               const float* __restrict__ rois, const float4* __restrict__ PD,
               const float* __restrict__ Wg_w, const float* __restrict__ Wg_b,
               u16* __restrict__ POSW, const int* __restrict__ n1b_p,
               const int* __restrict__ n1p_p, int PT) {
    __shared__ __align__(16) u16 SH[16896];   // 33 KB

    const int grp = blockIdx.x / 11, rem = blockIdx.x % 11;
    const int t = threadIdx.x;
    const int w = t >> 6, lane = t & 63;
    const int fm = lane & 15, quad = lane >> 4;

    if (rem < 3) {
        // ================= proj path =================
        u16* As = SH;             // [128][64]  16 KB
        u16* Ws = SH + 8192;      // [64][64]    8 KB
        u16* Tr = SH;             // aliases As/Ws after the k-loop (8704 u16)
        const int pb = grp * 3 + rem;
        const int z = pb >> 8;
        const int m0 = ((pb >> 4) & 15) * 128, j0 = (pb & 15) * 64;
        const u16* A = (z == 0) ? Ab : Pb;
        const u16* W = (z == 0) ? Wqb : (z == 1 ? Wkb : Cwb);
        const int wm = w >> 1, wn = w & 1;
        const int lr = lane >> 3, lc = lane & 7, gch = lc ^ lr;

        float4v zero4 = {0.f, 0.f, 0.f, 0.f};
        float4v acc[4][2];
#pragma unroll
        for (int i = 0; i < 4; ++i) { acc[i][0] = zero4; acc[i][1] = zero4; }

        for (int k0 = 0; k0 < 1024; k0 += 64) {
#pragma unroll
            for (int i = 0; i < 4; ++i) {
                int row = w * 32 + i * 8 + lr;
                dma16(A + (size_t)(m0 + row) * 1024 + k0 + gch * 8,
                      As + (w * 32 + i * 8) * 64 + lane * 8);
            }
#pragma unroll
            for (int i = 0; i < 2; ++i) {
                int row = w * 16 + i * 8 + lr;
                dma16(W + (size_t)(j0 + row) * 1024 + k0 + gch * 8,
                      Ws + (w * 16 + i * 8) * 64 + lane * 8);
            }
            __syncthreads();
#pragma unroll
            for (int ks = 0; ks < 2; ++ks) {
                int c = ks * 4 + quad;
                short8 af[4], bf[2];
#pragma unroll
                for (int i = 0; i < 4; ++i) {
                    int ra = wm * 64 + i * 16 + fm;
                    af[i] = *(const short8*)(As + ra * 64 + ((c ^ (ra & 7)) * 8));
                }
#pragma unroll
                for (int j = 0; j < 2; ++j) {
                    int rb = wn * 32 + j * 16 + fm;
                    bf[j] = *(const short8*)(Ws + rb * 64 + ((c ^ (rb & 7)) * 8));
                }
#pragma unroll
                for (int i = 0; i < 4; ++i)
#pragma unroll
                    for (int j = 0; j < 2; ++j)
                        acc[i][j] = __builtin_amdgcn_mfma_f32_16x16x32_bf16(af[i], bf[j], acc[i][j], 0, 0, 0);
            }
            __syncthreads();
        }
        // k-loop ended with a barrier: As/Ws dead, Tr (alias) safe to write.

        if (z < 2) {
            u16* O = z ? Kb : Qb;
            const float* bias = z ? bk : bq;
            // Tr as [ml 128][jl 64] stride 68
#pragma unroll
            for (int j = 0; j < 2; ++j) {
                int jl = wn * 32 + j * 16 + fm;
                float bb = bias[j0 + jl];
#pragma unroll
                for (int i = 0; i < 4; ++i) {
                    int mlb = wm * 64 + i * 16 + quad * 4;
#pragma unroll
                    for (int r = 0; r < 4; ++r)
                        Tr[(mlb + r) * 68 + jl] = f2bf(acc[i][j][r] + bb);
                }
            }
            __syncthreads();
#pragma unroll
            for (int i2 = 0; i2 < 4; ++i2) {
                int f = i2 * 2048 + t * 8;
                int ml = f >> 6, jl = f & 63;
                union { uint2 u2[2]; short8 s8; } uu;
                uu.u2[0] = *(const uint2*)(Tr + ml * 68 + jl);
                uu.u2[1] = *(const uint2*)(Tr + ml * 68 + jl + 4);
                *(short8*)(O + (size_t)(m0 + ml) * 1024 + j0 + jl) = uu.s8;
            }
        } else {
            // Tr as [jl 64][ml 128] stride 136
#pragma unroll
            for (int j = 0; j < 2; ++j) {
                int jl = wn * 32 + j * 16 + fm;
#pragma unroll
                for (int i = 0; i < 4; ++i) {
                    int mlb = wm * 64 + i * 16 + quad * 4;
                    uint2 pk;
                    pk.x = pkbf(acc[i][j][0], acc[i][j][1]);
                    pk.y = pkbf(acc[i][j][2], acc[i][j][3]);
                    *(uint2*)(Tr + jl * 136 + mlb) = pk;
                }
            }
            __syncthreads();
#pragma unroll
            for (int i2 = 0; i2 < 4; ++i2) {
                int f = i2 * 2048 + t * 8;
                int jl = f >> 7, ml = f & 127;
                union { uint2 u2[2]; short8 s8; } uu;
                uu.u2[0] = *(const uint2*)(Tr + jl * 136 + ml);
                uu.u2[1] = *(const uint2*)(Tr + jl * 136 + ml + 4);
                *(short8*)(PVt + (size_t)(j0 + jl) * PT + m0 + ml) = uu.s8;
            }
        }
        return;
    }

    // ================= posw path (r3 sin-chain) =================
    // Per-wave LDS stage: 16 iters x 264 u16 (4224 u16/wave, 16896 total).
    // [iter][(quad*16+fm)*4 + r] holds g=fm, p = iter*16 + quad*4 + r.
    u16* Wl = SH + w * 4224;

    const int n = grp * 8 + (rem - 3);
    const int n1b = *n1b_p, n1p = *n1p_p;
    const int hh = (n >= n1b) ? 1 : 0;
    const int p0 = hh ? n1p : 0;
    const int Ph = hh ? (PT - n1p) : n1p;   // 1024

    // n-box (block-uniform)
    float xmin = rois[n * 5 + 1], ymin = rois[n * 5 + 2];
    float xmax = rois[n * 5 + 3], ymax = rois[n * 5 + 4];
    float bw = xmax - xmin + 1.0f, bh = ymax - ymin + 1.0f;
    float cx = 0.5f * (xmin + xmax), cy = 0.5f * (ymin + ymax);

    const int jA = quad >> 1, trig = quad & 1;
    float cA   = (jA == 0) ? cx : cy;
    float invA = (jA == 0) ? (1.0f / bw) : (1.0f / bh);
    float lB   = (jA == 0) ? __logf(bw) : __logf(bh);
    float toff = trig ? 0.25f : 0.0f;

    // Wg b-fragments in registers; bias folded into acc init
    const int g_ = fm;
    short8 b1, b2;
    {
        const float* w1 = Wg_w + g_ * 64 + quad * 8;
        const float* w2 = Wg_w + g_ * 64 + 32 + quad * 8;
        unsigned* p1 = (unsigned*)&b1;
        unsigned* p2 = (unsigned*)&b2;
#pragma unroll
        for (int kk = 0; kk < 4; ++kk) {
            p1[kk] = pkbf(w1[2 * kk], w1[2 * kk + 1]);
            p2[kk] = pkbf(w2[2 * kk], w2[2 * kk + 1]);
        }
    }
    float wgb = Wg_b[g_];

    const float inv_em[8] = {1.0f, 0.4216965034f, 0.1778279410f, 0.0749894209f,
                             0.0316227766f, 0.0133352143f, 0.0056234133f, 0.0023713737f};
    const float REV = 15.91549431f;  // 100 / (2*pi)
    const int prange = Ph >> 2;      // p per wave (256)
    const int pb0 = w * prange;

    // software pipeline: prefetch PD one tile ahead
    float4 pd_c = PD[p0 + pb0 + fm];

#pragma unroll 2
    for (int pt = 0; pt < 16; ++pt) {
        float4 pd_n;
        if (pt < 15) pd_n = PD[p0 + pb0 + pt * 16 + 16 + fm];
        float pc = (jA == 0) ? pd_c.x : pd_c.y;
        float lp = (jA == 0) ? pd_c.z : pd_c.w;
        float posA = __logf(fmaxf(fabsf(cA - pc) * invA, 0.001f));
        float posB = lp - lB;
        float br1 = posA * REV, br2 = posB * REV;
        float e1[8], e2[8];
#pragma unroll
        for (int k = 0; k < 8; ++k) {
            e1[k] = sin_rev(fmaf(br1, inv_em[k], toff));
            e2[k] = sin_rev(fmaf(br2, inv_em[k], toff));
        }
        short8 a1, a2;
        unsigned* pa1 = (unsigned*)&a1;
        unsigned* pa2 = (unsigned*)&a2;
#pragma unroll
        for (int kk = 0; kk < 4; ++kk) {
            pa1[kk] = pkbf(e1[2 * kk], e1[2 * kk + 1]);
            pa2[kk] = pkbf(e2[2 * kk], e2[2 * kk + 1]);
        }
        float4v acc = {wgb, wgb, wgb, wgb};
        acc = __builtin_amdgcn_mfma_f32_16x16x32_bf16(a1, b1, acc, 0, 0, 0);
        acc = __builtin_amdgcn_mfma_f32_16x16x32_bf16(a2, b2, acc, 0, 0, 0);

        float w0  = fmaxf(acc[0], 1e-6f);
        float w1v = fmaxf(acc[1], 1e-6f);
        float w2v = fmaxf(acc[2], 1e-6f);
        float w3v = fmaxf(acc[3], 1e-6f);
        uint2 wp; wp.x = pkbf(w0, w1v); wp.y = pkbf(w2v, w3v);
        *(uint2*)(Wl + pt * 264 + lane * 4) = wp;   // lane == quad*16+fm

        pd_c = pd_n;
    }

    // coalesced flush: per sub-iter, 2 g-rows x 32 lanes x 16B = full 512B rows
    const int p8 = (lane & 31) * 8;      // p start within this wave's 256
    const int halfg = lane >> 5;         // 0/1
    const int itq = p8 >> 4;             // source iter
    const int q0 = (p8 >> 2) & 3;        // 0 or 2
#pragma unroll
    for (int s = 0; s < 8; ++s) {
        int gg = s * 2 + halfg;
        union { uint2 u2[2]; short8 s8; } uu;
        uu.u2[0] = *(const uint2*)(Wl + itq * 264 + (q0 * 16 + gg) * 4);
        uu.u2[1] = *(const uint2*)(Wl + itq * 264 + ((q0 + 1) * 16 + gg) * 4);
        *(short8*)(POSW + ((size_t)n * 16 + gg) * 1024 + pb0 + p8) = uu.s8;
    }
}

// ---------------------------------------------------------------------------
// fused_rel (r6 v3): att^T = mfma(K,Q) (lane-local w-phase) + T14 reg-staging.
// In-loop transport is global_load->VGPR + late ds_write (NO dma16 in loop),
// so barriers need only lgkmcnt: K/V waits retire 1 tile after issue (L2),
// POSW waits retire 2 tiles after issue (HBM).  ONE __syncthreads per p-tile.
// Grid (NT/64, 16) = 512 blocks; LDS 64 KB -> 2 blocks/CU.
// ---------------------------------------------------------------------------
__global__ __launch_bounds__(256)
void fused_rel(const u16* __restrict__ Qb, const u16* __restrict__ Kb,
               const u16* __restrict__ POSW, const u16* __restrict__ PVt,
               const float* __restrict__ conv_b, float* __restrict__ OUT,
               const int* __restrict__ n1b_p, const int* __restrict__ n1p_p, int PT) {
    __shared__ __align__(16) u16 Qs[64 * 64];        // 8 KB
    __shared__ __align__(16) u16 Ks[2][64 * 64];     // 16 KB
    __shared__ __align__(16) u16 Ps[2][64 * 64];     // 16 KB
    __shared__ __align__(16) u16 Vs[2][64 * 64];     // 16 KB
    __shared__ __align__(16) u16 Wt[4][16 * 64];     // 8 KB (wave-private rows)

    const int n0 = blockIdx.x * 64, g = blockIdx.y;
    const int n1b = *n1b_p, n1p = *n1p_p;
    const int hh = (n0 >= n1b) ? 1 : 0;
    const int p0 = hh ? n1p : 0;
    const int Ph = hh ? (PT - n1p) : n1p;
    const int t = threadIdx.x;
    const int w = t >> 6, lane = t & 63;
    const int lr = lane >> 3, lc = lane & 7, gch = lc ^ lr;
    const int fm = lane & 15, quad = lane >> 4;
    const int swz = fm & 7;

    // per-lane element-offset bases for the two 16B chunks each lane moves
    const int row0 = w * 16 + lr, row1 = w * 16 + 8 + lr;
    const size_t kb0 = (size_t)(p0 + row0) * 1024 + g * 64 + gch * 8;
    const size_t kb1 = (size_t)(p0 + row1) * 1024 + g * 64 + gch * 8;
    const size_t vb0 = (size_t)(g * 64 + row0) * PT + p0 + gch * 8;
    const size_t vb1 = (size_t)(g * 64 + row1) * PT + p0 + gch * 8;
    const size_t pbs0 = ((size_t)(n0 + row0) * 16 + g) * 1024 + gch * 8;
    const size_t pbs1 = ((size_t)(n0 + row1) * 16 + g) * 1024 + gch * 8;
    const int d0 = (w * 16) * 64 + lane * 8;
    const int d1 = (w * 16 + 8) * 64 + lane * 8;

    // prologue: Q via dma16 (drained once at prologue barrier); tile 0 K/V/P
    // via regs; P(1) issued deep.
    dma16(Qb + (size_t)(n0 + row0) * 1024 + g * 64 + gch * 8, Qs + d0);
    dma16(Qb + (size_t)(n0 + row1) * 1024 + g * 64 + gch * 8, Qs + d1);
    {
        uint4 ka = *(const uint4*)(Kb + kb0), kbv = *(const uint4*)(Kb + kb1);
        uint4 va = *(const uint4*)(PVt + vb0), vb = *(const uint4*)(PVt + vb1);
        uint4 pa = *(const uint4*)(POSW + pbs0), pbv = *(const uint4*)(POSW + pbs1);
        *(uint4*)(Ks[0] + d0) = ka;  *(uint4*)(Ks[0] + d1) = kbv;
        *(uint4*)(Vs[0] + d0) = va;  *(uint4*)(Vs[0] + d1) = vb;
        *(uint4*)(Ps[0] + d0) = pa;  *(uint4*)(Ps[0] + d1) = pbv;
    }
    uint4 prH0 = *(const uint4*)(POSW + pbs0 + 64);   // P(1)
    uint4 prH1 = *(const uint4*)(POSW + pbs1 + 64);

    float4v zero4 = {0.f, 0.f, 0.f, 0.f};
    float4v oacc[4];
#pragma unroll
    for (int ob = 0; ob < 4; ++ob) oacc[ob] = zero4;
    float rsum = 0.0f;

    __syncthreads();

    const int nloc = w * 16 + fm;
    // hoist Q fragments (B-operand rows = n); Qs stable from here on
    short8 qf[2];
#pragma unroll
    for (int kd = 0; kd < 2; ++kd) {
        int c = kd * 4 + quad;
        qf[kd] = *(const short8*)(Qs + nloc * 64 + ((c ^ swz) * 8));
    }
    u16* wrow = Wt[w] + fm * 64;

    const int NPT = Ph >> 6;   // 16
    for (int pt = 0; pt < NPT; ++pt) {
        const int cur = pt & 1, nxt = cur ^ 1;
        const u16* ks_ = Ks[cur];
        const u16* ps_ = Ps[cur];
        const u16* vs_ = Vs[cur];
        const bool have1 = (pt + 1 < NPT), have2 = (pt + 2 < NPT);

        // issue-early: K/V(pt+1) and POSW(pt+2) -> regs
        uint4 kra, krb, vra, vrb, prN0, prN1;
        if (have1) {
            size_t o = (size_t)(pt + 1) * 65536;
            kra = *(const uint4*)(Kb + kb0 + o);
            krb = *(const uint4*)(Kb + kb1 + o);
            vra = *(const uint4*)(PVt + vb0 + (pt + 1) * 64);
            vrb = *(const uint4*)(PVt + vb1 + (pt + 1) * 64);
        }
        if (have2) {
            prN0 = *(const uint4*)(POSW + pbs0 + (pt + 2) * 64);
            prN1 = *(const uint4*)(POSW + pbs1 + (pt + 2) * 64);
        }

        // att^T = mfma(K, Q): C[p-row = quad*4+r][n-col = fm]
        float4v atc[4];
#pragma unroll
        for (int pi = 0; pi < 4; ++pi) atc[pi] = zero4;
#pragma unroll
        for (int kd = 0; kd < 2; ++kd) {
            int c = kd * 4 + quad;
#pragma unroll
            for (int pi = 0; pi < 4; ++pi) {
                int rp = pi * 16 + fm;
                short8 kf = *(const short8*)(ks_ + rp * 64 + ((c ^ swz) * 8));
                atc[pi] = __builtin_amdgcn_mfma_f32_16x16x32_bf16(kf, qf[kd], atc[pi], 0, 0, 0);
            }
        }

        // w-phase (register-resident, wave-local): lane's n = nloc,
        // p = pi*16 + quad*4 + r.
#pragma unroll
        for (int pi = 0; pi < 4; ++pi) {
            int co = ((pi * 2 + (quad >> 1)) ^ swz) * 8 + (quad & 1) * 4;  // u16 units
            uint2 pwp = *(const uint2*)(ps_ + nloc * 64 + co);
            const u16* pww = (const u16*)&pwp;
            float wv0 = bf2f(pww[0]) * __expf(atc[pi][0] * 0.0625f);
            float wv1 = bf2f(pww[1]) * __expf(atc[pi][1] * 0.0625f);
            float wv2 = bf2f(pww[2]) * __expf(atc[pi][2] * 0.0625f);
            float wv3 = bf2f(pww[3]) * __expf(atc[pi][3] * 0.0625f);
            rsum += (wv0 + wv1) + (wv2 + wv3);
            uint2 wp; wp.x = pkbf(wv0, wv1); wp.y = pkbf(wv2, wv3);
            *(uint2*)(wrow + co) = wp;
        }

        // PV: out[n][o] += w[n,p] . V[o,p]; A-frag from wave-private Wt
#pragma unroll
        for (int m = 0; m < 2; ++m) {
            short8 af = *(const short8*)(wrow + (((m * 4 + quad) ^ swz) * 8));
#pragma unroll
            for (int ob = 0; ob < 4; ++ob) {
                int ro = ob * 16 + fm;
                short8 vf = *(const short8*)(vs_ + ro * 64 + (((m * 4 + quad) ^ swz) * 8));
                oacc[ob] = __builtin_amdgcn_mfma_f32_16x16x32_bf16(af, vf, oacc[ob], 0, 0, 0);
            }
        }

        // write-late: next-tile data into [nxt]; vmcnt waits sit HERE, with
        // K/V aged ~1 compute phase and POSW aged >= 1 full tile.
        if (have1) {
            *(uint4*)(Ks[nxt] + d0) = kra;  *(uint4*)(Ks[nxt] + d1) = krb;
            *(uint4*)(Vs[nxt] + d0) = vra;  *(uint4*)(Vs[nxt] + d1) = vrb;
            *(uint4*)(Ps[nxt] + d0) = prH0; *(uint4*)(Ps[nxt] + d1) = prH1;
            prH0 = prN0; prH1 = prN1;
        }

        __syncthreads();   // lgkm drain publishes [nxt]; no dma16 in flight
    }

    // rsum: lane-local over its p-subset -> reduce across the 4 quads
    float s = rsum;
    s += __shfl_xor(s, 16, 64);
    s += __shfl_xor(s, 32, 64);
    // oacc rows are n = w*16 + quad*4 + r; sums live at lane (quad*4+r) (quad0)
    float inv[4];
#pragma unroll
    for (int r = 0; r < 4; ++r)
        inv[r] = 1.0f / __shfl(s, quad * 4 + r, 64);

    float bb[4];
#pragma unroll
    for (int ob = 0; ob < 4; ++ob) bb[ob] = conv_b[g * 64 + ob * 16 + fm];
#pragma unroll
    for (int ob = 0; ob < 4; ++ob)
#pragma unroll
        for (int r = 0; r < 4; ++r) {
            int nn = n0 + w * 16 + quad * 4 + r;
            OUT[(size_t)nn * 1024 + g * 64 + ob * 16 + fm] = oacc[ob][r] * inv[r] + bb[ob];
        }
}

extern "C" void kernel_launch(void* const* d_in, const int* in_sizes, int n_in,
                              void* d_out, int out_size, void* d_ws, size_t ws_size,
                              hipStream_t stream) {
    const float* rois   = (const float*)d_in[0];
    const float* prois  = (const float*)d_in[1];
    const float* bfeat  = (const float*)d_in[2];
    const float* pfeat  = (const float*)d_in[3];
    const float* Wg_w   = (const float*)d_in[4];
    const float* Wg_b   = (const float*)d_in[5];
    const float* Wq_w   = (const float*)d_in[6];
    const float* Wq_b   = (const float*)d_in[7];
    const float* Wk_w   = (const float*)d_in[8];
    const float* Wk_b   = (const float*)d_in[9];
    const float* conv_w = (const float*)d_in[10];
    const float* conv_b = (const float*)d_in[11];
    const int*   n1b    = (const int*)d_in[12];
    const int*   n1p    = (const int*)d_in[13];

    const int NT = in_sizes[2] / 1024;  // 2048
    const int PT = in_sizes[3] / 1024;  // 2048

    u16* Qb   = (u16*)d_ws;                          // [NT][1024]
    u16* Kb   = Qb + (size_t)NT * 1024;              // [PT][1024]
    u16* PVt  = Kb + (size_t)PT * 1024;              // [1024][PT]
    float4* PD = (float4*)(PVt + (size_t)1024 * PT); // [PT]
    u16* POSW = (u16*)(PD + PT);                     // [NT][16][1024]
    u16* Ab   = POSW + (size_t)NT * 16 * 1024;       // bf16 staging (proj inputs)
    u16* Pb   = Ab + (size_t)NT * 1024;
    u16* Wqb  = Pb + (size_t)PT * 1024;
    u16* Wkb  = Wqb + 1024 * 1024;
    u16* Cwb  = Wkb + 1024 * 1024;

    dim3 blk(256);
    int nf4 = NT * 1024 / 4, pf4 = PT * 1024 / 4, wf4 = 1024 * 1024 / 4;
    int tot = nf4 + pf4 + 3 * wf4 + PT;
    cvt_all<<<dim3((tot + 255) / 256), blk, 0, stream>>>(
        bfeat, pfeat, Wq_w, Wk_w, conv_w, prois, Ab, Pb, Wqb, Wkb, Cwb, PD,
        nf4, pf4, wf4, PT);

    // 768 proj blocks + NT posw blocks, interleaved 3:8 per group of 11.
    proj_posw<<<dim3(256 * 11), blk, 0, stream>>>(Ab, Pb, Wqb, Wkb, Cwb,
                                                  Wq_b, Wk_b, Qb, Kb, PVt,
                                                  rois, PD, Wg_w, Wg_b, POSW,
                                                  n1b, n1p, PT);
    fused_rel<<<dim3(NT / 64, 16), blk, 0, stream>>>(Qb, Kb, POSW, PVt, conv_b,
                                                     (float*)d_out, n1b, n1p, PT);
}